// Round 3
// baseline (587.659 us; speedup 1.0000x reference)
//
#include <hip/hip_runtime.h>
#include <hip/hip_bf16.h>
#include <stdint.h>

#define T_DIM 256
#define B_DIM 64
#define DICO  8192
#define EMB   256
#define LAT   256
#define M_DIM (T_DIM*B_DIM)   /* 16384 */

#define BM 128
#define BN 256
#define BK 64
#define KSPLIT 2
#define KCHUNK (DICO/KSPLIT)  /* 4096 */
#define NKS (KCHUNK/BK)       /* 64 */

typedef short  bf16x8 __attribute__((ext_vector_type(8)));
typedef float  f32x4  __attribute__((ext_vector_type(4)));
typedef _Float16 f16x2 __attribute__((ext_vector_type(2)));

__device__ __forceinline__ ushort f2bf(float f) {
  uint32_t u = __float_as_uint(f);
  u += 0x7FFFu + ((u >> 16) & 1u);     // round-to-nearest-even
  return (ushort)(u >> 16);
}

__device__ __forceinline__ void glds16(const void* g, void* l) {
  __builtin_amdgcn_global_load_lds(
      (const __attribute__((address_space(1))) uint32_t*)g,
      (__attribute__((address_space(3))) uint32_t*)l, 16, 0, 0);
}

// ---------------- Kernel 1: Wct[n][k] = sum_e W_emb[k][e] * W_enc[e][n], bf16, n-major
__global__ void wct_kernel(const float* __restrict__ Wemb, const float* __restrict__ Wenc,
                           ushort* __restrict__ wct) {
  const int n  = threadIdx.x;          // 0..255
  const int d0 = blockIdx.x * 32;      // 256 blocks
  __shared__ float we[32 * 256];
  __shared__ float tr[32 * 257];
  #pragma unroll
  for (int r = 0; r < 32; ++r) we[r*256 + n] = Wemb[(size_t)(d0 + r)*EMB + n];
  __syncthreads();
  float acc[32];
  #pragma unroll
  for (int d = 0; d < 32; ++d) acc[d] = 0.f;
  for (int e = 0; e < 256; ++e) {
    float wv = Wenc[e*LAT + n];
    #pragma unroll
    for (int d = 0; d < 32; ++d) acc[d] += we[d*256 + e] * wv;   // LDS broadcast
  }
  #pragma unroll
  for (int d = 0; d < 32; ++d) tr[d*257 + n] = acc[d];
  __syncthreads();
  const int nn0 = n >> 2, kc = n & 3;
  #pragma unroll
  for (int p = 0; p < 4; ++p) {
    int nn = p*64 + nn0;
    bf16x8 v;
    #pragma unroll
    for (int j = 0; j < 8; ++j) v[j] = (short)f2bf(tr[(kc*8 + j)*257 + nn]);
    *(bf16x8*)(wct + (size_t)nn*DICO + d0 + kc*8) = v;
  }
}

// ---------------- Kernel 2: xp_part[ksp] = x[:, kchunk] @ Wc[kchunk, :]
// 2-phase pipeline. (256,1): LDS (96KB) caps at 1 block/CU anyway; uncapping
// VGPRs to 512 removes the loop-carried spills that (256,2)'s 256-cap forced
// (acc 128 + av 32 + bfr 32 + frags + addr > 256).
__global__ void __launch_bounds__(256, 1) gemm_kernel(const float* __restrict__ x,
                                                      const ushort* __restrict__ wct,
                                                      float* __restrict__ xp) {
  __shared__ __align__(16) ushort sA[2][BM * BK];   // frag-order, 16 KB each
  __shared__ __align__(16) ushort sB[2][BN * BK];   // frag-order, 32 KB each
  const int tid = threadIdx.x;
  const int bid = blockIdx.x;                        // 256 blocks
  const int swzb = (bid & 7) * 32 + (bid >> 3);      // XCD-contiguous (256%8==0)
  const int mt = swzb & 127, ksp = swzb >> 7;        // same-XCD blocks share ksp (B L2-resident)
  const size_t rowbase = (size_t)mt * BM;
  const int kbase = ksp * KCHUNK;

  const int lane = tid & 63, wid = tid >> 6;
  const int l15 = lane & 15, lc = lane >> 4;

  // A staging: thread owns segments tid and tid+256; seg s: row=s>>2, 16-float chunk=s&3
  const int r0 = tid >> 2, c0 = tid & 3;
  const float* ag0 = x + (rowbase + r0) * (size_t)DICO + kbase + c0 * 16;
  const float* ag1 = ag0 + (size_t)64 * DICO;
  // frag-order dst: group=(row>>4)*2+(chunk>>1), lane_slot=(row&15)+(chunk&1)*32 (+16 for hi 8)
  const int aw0 = ((((r0      ) >> 4) * 2 + (c0 >> 1)) * 64 + (r0 & 15) + (c0 & 1) * 32) * 16;
  const int aw1 = ((((r0 + 64 ) >> 4) * 2 + (c0 >> 1)) * 64 + (r0 & 15) + (c0 & 1) * 32) * 16;

  const char* wb = (const char*)wct;
  const size_t kb2 = (size_t)kbase * 2;

  f32x4 acc[8][4];
  #pragma unroll
  for (int m = 0; m < 8; ++m)
    #pragma unroll
    for (int n = 0; n < 4; ++n) acc[m][n] = (f32x4){0.f, 0.f, 0.f, 0.f};

  float4 av[8];

  auto loadA = [&](int kofs) {
    #pragma unroll
    for (int q = 0; q < 4; ++q) av[q]     = *(const float4*)(ag0 + kofs + q * 4);
    #pragma unroll
    for (int q = 0; q < 4; ++q) av[4 + q] = *(const float4*)(ag1 + kofs + q * 4);
  };
  auto stageB = [&](int buf, int kofs) {
    // group g=r*4+wid holds (nfrag=g>>1, k2=g&1); lane l: col16=l&15 -> wct row, lc -> k sub-8
    #pragma unroll
    for (int r = 0; r < 8; ++r) {
      const int g = r * 4 + wid;
      const int srow  = (g >> 1) * 16 + l15;
      const int skoff = (g & 1) * 32 + lc * 8;
      glds16(wb + (size_t)srow * (DICO * 2) + kb2 + (size_t)(kofs + skoff) * 2,
             (char*)&sB[buf][0] + r * 4096 + tid * 16);
    }
  };
  auto storeA = [&](int buf) {
    #pragma unroll
    for (int h = 0; h < 2; ++h) {
      const float4 a0 = av[h*4+0], a1 = av[h*4+1], a2 = av[h*4+2], a3 = av[h*4+3];
      bf16x8 w0, w1;
      w0[0]=(short)f2bf(a0.x); w0[1]=(short)f2bf(a0.y); w0[2]=(short)f2bf(a0.z); w0[3]=(short)f2bf(a0.w);
      w0[4]=(short)f2bf(a1.x); w0[5]=(short)f2bf(a1.y); w0[6]=(short)f2bf(a1.z); w0[7]=(short)f2bf(a1.w);
      w1[0]=(short)f2bf(a2.x); w1[1]=(short)f2bf(a2.y); w1[2]=(short)f2bf(a2.z); w1[3]=(short)f2bf(a2.w);
      w1[4]=(short)f2bf(a3.x); w1[5]=(short)f2bf(a3.y); w1[6]=(short)f2bf(a3.z); w1[7]=(short)f2bf(a3.w);
      char* base = (char*)&sA[buf][0] + (h ? aw1 : aw0);
      *(bf16x8*)(base)       = w0;
      *(bf16x8*)(base + 256) = w1;
    }
  };
  auto compute = [&](int buf) {
    bf16x8 bfr[4][2];
    #pragma unroll
    for (int n = 0; n < 4; ++n)
      #pragma unroll
      for (int k2 = 0; k2 < 2; ++k2)
        bfr[n][k2] = *(const bf16x8*)((char*)&sB[buf][0] + ((((wid*4 + n)*2 + k2) * 64 + lane) * 16));
    #pragma unroll
    for (int m = 0; m < 8; ++m) {
      bf16x8 a0 = *(const bf16x8*)((char*)&sA[buf][0] + (((m*2 + 0) * 64 + lane) * 16));
      bf16x8 a1 = *(const bf16x8*)((char*)&sA[buf][0] + (((m*2 + 1) * 64 + lane) * 16));
      #pragma unroll
      for (int n = 0; n < 4; ++n) {
        acc[m][n] = __builtin_amdgcn_mfma_f32_16x16x32_bf16(a0, bfr[n][0], acc[m][n], 0, 0, 0);
        acc[m][n] = __builtin_amdgcn_mfma_f32_16x16x32_bf16(a1, bfr[n][1], acc[m][n], 0, 0, 0);
      }
    }
  };

  // prologue
  loadA(0);
  stageB(0, 0);
  storeA(0);
  __syncthreads();

  int cur = 0;
  for (int ks = 0; ks < NKS; ++ks) {
    const int kn = (ks + 1) * BK;
    if (ks + 1 < NKS) { loadA(kn); stageB(cur ^ 1, kn); }  // A first in vmcnt FIFO
    compute(cur);
    if (ks + 1 < NKS) storeA(cur ^ 1);                      // waits vmcnt(8): A only
    __syncthreads();                                        // drains glds for next compute
    cur ^= 1;
  }

  float* xpo = xp + ((size_t)ksp * M_DIM + rowbase) * LAT;
  #pragma unroll
  for (int m = 0; m < 8; ++m)
    #pragma unroll
    for (int n = 0; n < 4; ++n)
      #pragma unroll
      for (int j = 0; j < 4; ++j)
        xpo[(size_t)(m*16 + lc*4 + j) * LAT + wid*64 + n*16 + l15] = acc[m][n][j];
}

// ---------------- Kernel 3: per-b recurrence h = tanh(xp_t + bc + h@Wh)
// Key fix: __syncthreads() = s_waitcnt vmcnt(0) lgkmcnt(0) + s_barrier, which
// drained the global ob-store AND the t+2 xp prefetch EVERY step (exposed ~900cy
// HBM latency/step). Only LDS (hbuf) needs cross-wave visibility -> raw
// s_barrier with lgkmcnt(0)-only wait, pinned by sched_barrier(0) (rule #18).
__global__ void __launch_bounds__(256, 1) rnn_kernel(const float* __restrict__ xp,
                           const float* __restrict__ h0, const float* __restrict__ Wenc,
                           const float* __restrict__ bemb, const float* __restrict__ benc,
                           float* __restrict__ out) {
  const int b = blockIdx.x, l = threadIdx.x;       // 64 blocks x 256 threads
  __shared__ __align__(16) uint32_t hbuf[2][128];  // double-buffered h (f16)
  float bc = benc[l];
  #pragma unroll 8
  for (int e = 0; e < 256; ++e) bc += bemb[e] * Wenc[e*LAT + l];
  f16x2 wh[128];
  #pragma unroll
  for (int j = 0; j < 128; ++j) {
    f16x2 w;
    w[0] = (_Float16)Wenc[(size_t)(EMB + 2*j    )*LAT + l];
    w[1] = (_Float16)Wenc[(size_t)(EMB + 2*j + 1)*LAT + l];
    wh[j] = w;
  }
  ((_Float16*)&hbuf[0][0])[l] = (_Float16)h0[(size_t)b*LAT + l];
  __syncthreads();                                 // one-time full drain (prologue)
  const float* xpb = xp + (size_t)b*LAT + l;
  float*       ob  = out + (size_t)b*LAT + l;
  const size_t ST = (size_t)B_DIM * LAT;           // 16384
  const size_t PO = (size_t)M_DIM * LAT;           // partial offset
  // 2-step-ahead register prefetch of xp (ping-pong scalars, no arrays)
  float xa0 = xpb[0],  xa1 = xpb[PO];
  float xb0 = xpb[ST], xb1 = xpb[ST + PO];
  float xc0 = 0.f, xc1 = 0.f;
  for (int t = 0; t < T_DIM; ++t) {
    if (t + 2 < T_DIM) {
      size_t ni = (size_t)(t + 2) * ST;
      xc0 = xpb[ni]; xc1 = xpb[ni + PO];           // stays in flight across barriers now
    }
    const uint32_t* hc = &hbuf[t & 1][0];
    float s0=0.f,s1=0.f,s2=0.f,s3=0.f,s4=0.f,s5=0.f,s6=0.f,s7=0.f;
    #pragma unroll
    for (int q = 0; q < 16; ++q) {
      uint4 hv0 = *(const uint4*)(hc + q*8);       // LDS broadcast (uniform addr)
      uint4 hv1 = *(const uint4*)(hc + q*8 + 4);
      s0 = __builtin_amdgcn_fdot2(wh[q*8+0], __builtin_bit_cast(f16x2, hv0.x), s0, false);
      s1 = __builtin_amdgcn_fdot2(wh[q*8+1], __builtin_bit_cast(f16x2, hv0.y), s1, false);
      s2 = __builtin_amdgcn_fdot2(wh[q*8+2], __builtin_bit_cast(f16x2, hv0.z), s2, false);
      s3 = __builtin_amdgcn_fdot2(wh[q*8+3], __builtin_bit_cast(f16x2, hv0.w), s3, false);
      s4 = __builtin_amdgcn_fdot2(wh[q*8+4], __builtin_bit_cast(f16x2, hv1.x), s4, false);
      s5 = __builtin_amdgcn_fdot2(wh[q*8+5], __builtin_bit_cast(f16x2, hv1.y), s5, false);
      s6 = __builtin_amdgcn_fdot2(wh[q*8+6], __builtin_bit_cast(f16x2, hv1.z), s6, false);
      s7 = __builtin_amdgcn_fdot2(wh[q*8+7], __builtin_bit_cast(f16x2, hv1.w), s7, false);
    }
    float pre = (xa0 + xa1) + bc + (((s0+s1)+(s2+s3)) + ((s4+s5)+(s6+s7)));
    float ax = fabsf(pre);
    float e2 = __expf(-2.f * ax);
    float r  = __fdividef(1.f - e2, 1.f + e2);
    float hn = (pre < 0.f) ? -r : r;
    ob[(size_t)t * ST] = hn;                       // fire-and-forget (not drained)
    ((_Float16*)&hbuf[(t + 1) & 1][0])[l] = (_Float16)hn;
    __builtin_amdgcn_sched_barrier(0);
    asm volatile("s_waitcnt lgkmcnt(0)" ::: "memory");   // LDS write visible
    __builtin_amdgcn_s_barrier();                        // vmcnt NOT drained
    __builtin_amdgcn_sched_barrier(0);
    xa0 = xb0; xa1 = xb1; xb0 = xc0; xb1 = xc1;
  }
}

extern "C" void kernel_launch(void* const* d_in, const int* in_sizes, int n_in,
                              void* d_out, int out_size, void* d_ws, size_t ws_size,
                              hipStream_t stream) {
  const float* x    = (const float*)d_in[0];
  const float* h0   = (const float*)d_in[1];
  const float* Wemb = (const float*)d_in[2];
  const float* bemb = (const float*)d_in[3];
  const float* Wenc = (const float*)d_in[4];
  const float* benc = (const float*)d_in[5];
  float* out = (float*)d_out;

  ushort* wct = (ushort*)d_ws;                               // 4 MiB bf16 [256][8192]
  float*  xp  = (float*)((char*)d_ws + ((size_t)4 << 20));   // 2 x 16 MiB fp32 partials

  wct_kernel<<<256, 256, 0, stream>>>(Wemb, Wenc, wct);
  gemm_kernel<<<256, 256, 0, stream>>>(x, wct, xp);
  rnn_kernel<<<64, 256, 0, stream>>>(xp, h0, Wenc, bemb, benc, out);
}